// Round 1
// baseline (1234.902 us; speedup 1.0000x reference)
//
#include <hip/hip_runtime.h>
#include <math.h>

#define NN 100000
#define NE 1000000
#define F 32

// ---------------- degree accumulation ----------------
__global__ void k_deg(const int* __restrict__ ei, const float* __restrict__ ew,
                      float* __restrict__ deg_out, float* __restrict__ deg_in, int E) {
    int e = blockIdx.x * blockDim.x + threadIdx.x;
    if (e >= E) return;
    float w = ew[e];
    atomicAdd(&deg_out[ei[e]], w);       // by src
    atomicAdd(&deg_in[ei[E + e]], w);    // by dst
}

// ---------------- per-edge norms ----------------
__global__ void k_norm(const int* __restrict__ ei, const float* __restrict__ ew,
                       const float* __restrict__ deg_out, const float* __restrict__ deg_in,
                       float* __restrict__ norm_out, float* __restrict__ norm_in, int E) {
    int e = blockIdx.x * blockDim.x + threadIdx.x;
    if (e >= E) return;
    float w = ew[e];
    norm_out[e] = w / deg_out[ei[e]];
    norm_in[e]  = w / deg_in[ei[E + e]];
}

// ---------------- diffusion scatter (both directions in one pass) ----------------
// to[dst] += norm_out[e] * vo[src]   (forward random walk)
// ti[src] += norm_in[e]  * vi[dst]   (reverse random walk)
__global__ void k_scatter(const int* __restrict__ ei,
                          const float* __restrict__ norm_out, const float* __restrict__ norm_in,
                          const float* __restrict__ vo, const float* __restrict__ vi,
                          float* __restrict__ to, float* __restrict__ ti, int E) {
    long gid = (long)blockIdx.x * blockDim.x + threadIdx.x;
    int e = (int)(gid >> 5);
    int i = (int)(gid & 31);
    if (e >= E) return;
    int s = ei[e];
    int d = ei[E + e];
    atomicAdd(&to[d * F + i], norm_out[e] * vo[s * F + i]);
    atomicAdd(&ti[s * F + i], norm_in[e]  * vi[d * F + i]);
}

// ---------------- fused gates + GRU update + output head ----------------
// Effective per-gate pre-activation:
//   g = b + x*(W00+W10-W02-W12) + T1o*W01 + T1i*W11 + P2o*(2*W02) + P2i*(2*W12)
// where P2{o,i} are the raw hop-2 propagations (T2 = 2*P2 - x folded into weights).
__launch_bounds__(256)
__global__ void k_final(const float* __restrict__ x,
                        const float* __restrict__ t1o, const float* __restrict__ t1i,
                        const float* __restrict__ p2o, const float* __restrict__ p2i,
                        const float* __restrict__ Wz, const float* __restrict__ bz,
                        const float* __restrict__ Wh, const float* __restrict__ bh,
                        const float* __restrict__ Wl, const float* __restrict__ bl,
                        float* __restrict__ y, int n_nodes) {
    __shared__ float S[10][32][32];   // 5 combined mats for z, 5 for h (40 KB)

    // cooperative weight staging; W layout is (2,3,64,32) — only rows 0..31 used
    for (int idx = threadIdx.x; idx < 10 * 1024; idx += 256) {
        int mat  = idx >> 10;
        int rem  = idx & 1023;
        int i    = rem >> 5;
        int j    = rem & 31;
        const float* W = (mat < 5) ? Wz : Wh;
        int term = mat % 5;
#define WDK(d, k) W[((((d) * 3 + (k)) * 64 + i) * 32) + j]
        float v;
        if      (term == 0) v = WDK(0,0) + WDK(1,0) - WDK(0,2) - WDK(1,2);
        else if (term == 1) v = WDK(0,1);
        else if (term == 2) v = WDK(1,1);
        else if (term == 3) v = 2.0f * WDK(0,2);
        else                v = 2.0f * WDK(1,2);
#undef WDK
        S[mat][i][j] = v;
    }
    __syncthreads();

    int node = blockIdx.x * 8 + (threadIdx.x >> 5);
    int j = threadIdx.x & 31;
    if (node >= n_nodes) return;

    const float* xr = x   + (long)node * F;
    const float* ar = t1o + (long)node * F;
    const float* br = t1i + (long)node * F;
    const float* cr = p2o + (long)node * F;
    const float* dr = p2i + (long)node * F;

    float gz = bz[j];
    float gh = bh[j];
#pragma unroll
    for (int i = 0; i < 32; ++i) {
        float xi = xr[i], a = ar[i], b = br[i], c = cr[i], d = dr[i];
        gz += xi * S[0][i][j] + a * S[1][i][j] + b * S[2][i][j] + c * S[3][i][j] + d * S[4][i][j];
        gh += xi * S[5][i][j] + a * S[6][i][j] + b * S[7][i][j] + c * S[8][i][j] + d * S[9][i][j];
    }

    float z  = 1.0f / (1.0f + __expf(-gz));
    float ht = tanhf(gh);
    float Hj = (1.0f - z) * ht;              // H = (1-Z)*H_tilde   (H0 == 0)
    float r  = fmaxf(Hj, 0.0f) * Wl[j];      // relu(H) @ Wl

    // reduce across the 32 output channels (half-wave)
    for (int off = 16; off > 0; off >>= 1) r += __shfl_down(r, off, 32);
    if (j == 0) y[node] = r + bl[0];
}

extern "C" void kernel_launch(void* const* d_in, const int* in_sizes, int n_in,
                              void* d_out, int out_size, void* d_ws, size_t ws_size,
                              hipStream_t stream) {
    const float* x  = (const float*)d_in[0];
    const int*   ei = (const int*)  d_in[1];
    const float* ew = (const float*)d_in[2];
    // d_in[3] = h (unused: reference forces H0 = 0), d_in[4] = c (unused)
    const float* Wz = (const float*)d_in[5];
    const float* bz = (const float*)d_in[6];
    // d_in[7] = Wr, d_in[8] = br : dead code (R * H0 == 0)
    const float* Wh = (const float*)d_in[9];
    const float* bh = (const float*)d_in[10];
    const float* Wl = (const float*)d_in[11];
    const float* bl = (const float*)d_in[12];
    float* y = (float*)d_out;

    // workspace layout (floats)
    float* ws = (float*)d_ws;
    float* deg_out  = ws;                       // NN
    float* deg_in   = deg_out + NN;             // NN
    float* t1o      = deg_in  + NN;             // NN*F
    float* t1i      = t1o + (long)NN * F;       // NN*F
    float* p2o      = t1i + (long)NN * F;       // NN*F
    float* p2i      = p2o + (long)NN * F;       // NN*F
    float* norm_out = p2i + (long)NN * F;       // NE
    float* norm_in  = norm_out + NE;            // NE

    // zero the accumulators (degrees + 4 node-feature buffers)
    size_t zero_bytes = (size_t)(2 * NN + 4 * NN * F) * sizeof(float);
    hipMemsetAsync(d_ws, 0, zero_bytes, stream);

    const int B = 256;
    int gridE  = (NE + B - 1) / B;
    int gridEF = (int)(((long)NE * F + B - 1) / B);
    int gridN  = (NN + 7) / 8;

    k_deg<<<gridE, B, 0, stream>>>(ei, ew, deg_out, deg_in, NE);
    k_norm<<<gridE, B, 0, stream>>>(ei, ew, deg_out, deg_in, norm_out, norm_in, NE);
    // hop 1: T1o = prop_out(x), T1i = prop_in(x)
    k_scatter<<<gridEF, B, 0, stream>>>(ei, norm_out, norm_in, x, x, t1o, t1i, NE);
    // hop 2 (raw): P2o = prop_out(T1o), P2i = prop_in(T1i)
    k_scatter<<<gridEF, B, 0, stream>>>(ei, norm_out, norm_in, t1o, t1i, p2o, p2i, NE);
    // gates + GRU + head
    k_final<<<gridN, B, 0, stream>>>(x, t1o, t1i, p2o, p2i,
                                     Wz, bz, Wh, bh, Wl, bl, y, NN);
}

// Round 2
// 706.020 us; speedup vs baseline: 1.7491x; 1.7491x over previous
//
#include <hip/hip_runtime.h>
#include <math.h>

#define NN 100000
#define NE 1000000
#define F 32
#define TN 64          // nodes per k_final block
#define SPAD 68        // LDS row stride in floats (272 B, 16B-aligned)

// ---------------- degree accumulation ----------------
__global__ void k_deg(const int* __restrict__ ei, const float* __restrict__ ew,
                      float* __restrict__ deg_out, float* __restrict__ deg_in, int E) {
    int e = blockIdx.x * blockDim.x + threadIdx.x;
    if (e >= E) return;
    float w = ew[e];
    atomicAdd(&deg_out[ei[e]], w);       // by src
    atomicAdd(&deg_in[ei[E + e]], w);    // by dst
}

// ---------------- per-edge norms ----------------
__global__ void k_norm(const int* __restrict__ ei, const float* __restrict__ ew,
                       const float* __restrict__ deg_out, const float* __restrict__ deg_in,
                       float* __restrict__ norm_out, float* __restrict__ norm_in, int E) {
    int e = blockIdx.x * blockDim.x + threadIdx.x;
    if (e >= E) return;
    float w = ew[e];
    norm_out[e] = w / deg_out[ei[e]];
    norm_in[e]  = w / deg_in[ei[E + e]];
}

// ---------------- diffusion scatter (both directions in one pass) ----------------
__global__ void k_scatter(const int* __restrict__ ei,
                          const float* __restrict__ norm_out, const float* __restrict__ norm_in,
                          const float* __restrict__ vo, const float* __restrict__ vi,
                          float* __restrict__ to, float* __restrict__ ti, int E) {
    long gid = (long)blockIdx.x * blockDim.x + threadIdx.x;
    int e = (int)(gid >> 5);
    int i = (int)(gid & 31);
    if (e >= E) return;
    int s = ei[e];
    int d = ei[E + e];
    atomicAdd(&to[d * F + i], norm_out[e] * vo[s * F + i]);
    atomicAdd(&ti[s * F + i], norm_in[e]  * vi[d * F + i]);
}

// ---------------- fused gates + GRU + head: [100K x 160] @ [160 x 64] ----------------
// Combined weights (H0==0 folds K-hop recurrence):
//   col j<32  -> z gate, j>=32 -> h gate
//   row term 0: x      * (W00+W10-W02-W12)
//   row term 1: T1o    * W01
//   row term 2: T1i    * W11
//   row term 3: P2o    * 2*W02     (T2 = 2*P2 - x folded)
//   row term 4: P2i    * 2*W12
__launch_bounds__(256, 2)
__global__ void k_final(const float* __restrict__ x,
                        const float* __restrict__ t1o, const float* __restrict__ t1i,
                        const float* __restrict__ p2o, const float* __restrict__ p2i,
                        const float* __restrict__ Wz, const float* __restrict__ bz,
                        const float* __restrict__ Wh, const float* __restrict__ bh,
                        const float* __restrict__ Wl, const float* __restrict__ bl,
                        float* __restrict__ y, int n_nodes) {
    __shared__ float w_lds[160 * 64];      // 40960 B, combined weights [row][j]
    __shared__ float in_lds[TN * SPAD];    // 17408 B, transposed input tile [feat][node]; reused as g[node][j]

    const int tid = threadIdx.x;

    // ---- stage combined weights (only first 32 of 64 W-rows matter: H0 == 0) ----
    for (int idx = tid; idx < 160 * 64; idx += 256) {
        int i  = idx >> 6;        // 0..159
        int j  = idx & 63;
        int jc = j & 31;
        const float* W = (j >= 32) ? Wh : Wz;
        int term = i >> 5;
        int fi   = i & 31;
#define WDK(d, k) W[((((d) * 3 + (k)) * 64) + fi) * 32 + jc]
        float v;
        if      (term == 0) v = WDK(0,0) + WDK(1,0) - WDK(0,2) - WDK(1,2);
        else if (term == 1) v = WDK(0,1);
        else if (term == 2) v = WDK(1,1);
        else if (term == 3) v = 2.0f * WDK(0,2);
        else                v = 2.0f * WDK(1,2);
#undef WDK
        w_lds[idx] = v;
    }

    const int node0 = blockIdx.x * TN;
    const int nsub  = (tid & 15) * 4;     // 4-node sub-tile
    const int jsub  = (tid >> 4) * 4;     // 4-output sub-tile

    float acc[4][4];
#pragma unroll
    for (int a = 0; a < 4; ++a)
#pragma unroll
        for (int b = 0; b < 4; ++b) acc[a][b] = 0.0f;

    const float* arrs[5] = {x, t1o, t1i, p2o, p2i};

    int wrow = 0;
    for (int pass = 0; pass < 3; ++pass) {
        const int na = (pass == 2) ? 1 : 2;
        __syncthreads();                  // protect in_lds (and w_lds on pass 0)
        for (int a = 0; a < na; ++a) {
            const float* src = arrs[pass * 2 + a];
#pragma unroll
            for (int k = 0; k < 2; ++k) {
                int q  = tid + k * 256;   // 0..511
                int nl = q >> 3;          // local node 0..63
                int f4 = (q & 7) * 4;     // feat 0,4,...,28
                int ng = node0 + nl;
                float4 v = make_float4(0.f, 0.f, 0.f, 0.f);
                if (ng < n_nodes) v = *(const float4*)(src + (long)ng * F + f4);
                int rb = a * 32 + f4;
                in_lds[(rb + 0) * SPAD + nl] = v.x;
                in_lds[(rb + 1) * SPAD + nl] = v.y;
                in_lds[(rb + 2) * SPAD + nl] = v.z;
                in_lds[(rb + 3) * SPAD + nl] = v.w;
            }
        }
        __syncthreads();
        const int rows = na * 32;
#pragma unroll 8
        for (int i = 0; i < rows; ++i) {
            float4 av = *(const float4*)&in_lds[i * SPAD + nsub];
            float4 wv = *(const float4*)&w_lds[(wrow + i) * 64 + jsub];
            acc[0][0] += av.x * wv.x; acc[0][1] += av.x * wv.y; acc[0][2] += av.x * wv.z; acc[0][3] += av.x * wv.w;
            acc[1][0] += av.y * wv.x; acc[1][1] += av.y * wv.y; acc[1][2] += av.y * wv.z; acc[1][3] += av.y * wv.w;
            acc[2][0] += av.z * wv.x; acc[2][1] += av.z * wv.y; acc[2][2] += av.z * wv.z; acc[2][3] += av.z * wv.w;
            acc[3][0] += av.w * wv.x; acc[3][1] += av.w * wv.y; acc[3][2] += av.w * wv.z; acc[3][3] += av.w * wv.w;
        }
        wrow += rows;
    }

    // ---- epilogue: cross-thread combine via LDS (g[node][j] reuses in_lds) ----
    __syncthreads();
#pragma unroll
    for (int a = 0; a < 4; ++a)
#pragma unroll
        for (int b = 0; b < 4; ++b)
            in_lds[(nsub + a) * SPAD + (jsub + b)] = acc[a][b];
    __syncthreads();

    const int c  = tid & 31;
    const int nr = tid >> 5;              // 0..7
    const float wl  = Wl[c];
    const float bzv = bz[c];
    const float bhv = bh[c];
    const float blv = bl[0];
#pragma unroll
    for (int r = 0; r < 8; ++r) {
        int nl = r * 8 + nr;
        float gz = in_lds[nl * SPAD + c] + bzv;
        float gh = in_lds[nl * SPAD + 32 + c] + bhv;
        float z  = 1.0f / (1.0f + __expf(-gz));
        float e2 = __expf(2.0f * gh);
        float ht = 1.0f - 2.0f / (e2 + 1.0f);          // tanh
        float v  = fmaxf((1.0f - z) * ht, 0.0f) * wl;  // relu(H)*Wl, H=(1-Z)*Ht (H0==0)
        for (int off = 16; off > 0; off >>= 1) v += __shfl_down(v, off, 32);
        if (c == 0) {
            int ng = node0 + nl;
            if (ng < n_nodes) y[ng] = v + blv;
        }
    }
}

extern "C" void kernel_launch(void* const* d_in, const int* in_sizes, int n_in,
                              void* d_out, int out_size, void* d_ws, size_t ws_size,
                              hipStream_t stream) {
    const float* x  = (const float*)d_in[0];
    const int*   ei = (const int*)  d_in[1];
    const float* ew = (const float*)d_in[2];
    // d_in[3]=h, d_in[4]=c unused (H0 forced to 0); d_in[7]=Wr, d_in[8]=br dead (R*H0==0)
    const float* Wz = (const float*)d_in[5];
    const float* bz = (const float*)d_in[6];
    const float* Wh = (const float*)d_in[9];
    const float* bh = (const float*)d_in[10];
    const float* Wl = (const float*)d_in[11];
    const float* bl = (const float*)d_in[12];
    float* y = (float*)d_out;

    float* ws = (float*)d_ws;
    float* deg_out  = ws;                       // NN
    float* deg_in   = deg_out + NN;             // NN
    float* t1o      = deg_in  + NN;             // NN*F
    float* t1i      = t1o + (long)NN * F;       // NN*F
    float* p2o      = t1i + (long)NN * F;       // NN*F
    float* p2i      = p2o + (long)NN * F;       // NN*F
    float* norm_out = p2i + (long)NN * F;       // NE
    float* norm_in  = norm_out + NE;            // NE

    size_t zero_bytes = (size_t)(2 * NN + 4 * NN * F) * sizeof(float);
    hipMemsetAsync(d_ws, 0, zero_bytes, stream);

    const int B = 256;
    int gridE  = (NE + B - 1) / B;
    int gridEF = (int)(((long)NE * F + B - 1) / B);
    int gridN  = (NN + TN - 1) / TN;

    k_deg<<<gridE, B, 0, stream>>>(ei, ew, deg_out, deg_in, NE);
    k_norm<<<gridE, B, 0, stream>>>(ei, ew, deg_out, deg_in, norm_out, norm_in, NE);
    k_scatter<<<gridEF, B, 0, stream>>>(ei, norm_out, norm_in, x, x, t1o, t1i, NE);
    k_scatter<<<gridEF, B, 0, stream>>>(ei, norm_out, norm_in, t1o, t1i, p2o, p2i, NE);
    k_final<<<gridN, B, 0, stream>>>(x, t1o, t1i, p2o, p2i,
                                     Wz, bz, Wh, bh, Wl, bl, y, NN);
}